// Round 2
// baseline (30915.305 us; speedup 1.0000x reference)
//
#include <hip/hip_runtime.h>
#include <hip/hip_bf16.h>

// ViT-B/16 forward, MI355X. Round 1: all-fp32 I/O (per reference dtypes),
// fp32 compute. Correctness-first baseline; MFMA conversion next round.
//
// Shapes: B=32, IMG=224, PATCH=16 -> 196 patches +cls = 197 tokens,
// DIM=768, HEADS=12, HD=64, FF=3072, DEPTH=12, NRD=732.

#define B_     32
#define DIM_   768
#define N_     197
#define M_     (B_*N_)      // 6304 token rows
#define NP_    196
#define MP_    (B_*NP_)     // 6272 patch rows
#define HEADS_ 12
#define HD_    64
#define FF_    3072
#define NRD_   732
#define QKV_   2304

// ---------------- patchify: x[B,3,224,224] -> P[6272,768], k = c*256+py*16+px
__global__ void patchify_k(const float* __restrict__ X, float* __restrict__ P) {
    int idx = blockIdx.x * 256 + threadIdx.x;
    if (idx >= MP_ * DIM_) return;
    int row = idx / DIM_, k = idx - row * DIM_;
    int b = row / NP_, p = row - b * NP_;
    int gy = p / 14, gx = p - gy * 14;
    int c = k >> 8, r = k & 255;
    int py = r >> 4, px = r & 15;
    P[idx] = X[((b * 3 + c) * 224 + gy * 16 + py) * 224 + gx * 16 + px];
}

// ---------------- tokens: row t==0 -> cls, else patch output
__global__ void build_tokens_k(const float* __restrict__ P, const float* __restrict__ cls,
                               float* __restrict__ T) {
    int idx = blockIdx.x * 256 + threadIdx.x;
    if (idx >= M_ * DIM_) return;
    int row = idx / DIM_, c = idx - row * DIM_;
    int b = row / N_, t = row - b * N_;
    T[idx] = (t == 0) ? cls[c] : P[(size_t)(b * NP_ + t - 1) * DIM_ + c];
}

// ---------------- qkv bias = concat(q_bias, 0, v_bias)
__global__ void qkvbias_k(const float* __restrict__ qb, const float* __restrict__ vb,
                          float* __restrict__ out) {
    int n = blockIdx.x * 256 + threadIdx.x;
    if (n >= QKV_) return;
    out[n] = (n < DIM_) ? qb[n] : (n < 2 * DIM_ ? 0.f : vb[n - 2 * DIM_]);
}

// ---------------- LayerNorm (biased var, eps=1e-5). One block(256) per row.
__global__ void layernorm_k(const float* __restrict__ X, const float* __restrict__ w,
                            const float* __restrict__ bta, float* __restrict__ Y) {
    int row = blockIdx.x;
    const float* x = X + (size_t)row * DIM_;
    int t = threadIdx.x;
    float v[3]; float s = 0.f, q = 0.f;
#pragma unroll
    for (int i = 0; i < 3; i++) { float u = x[t + i * 256]; v[i] = u; s += u; q += u * u; }
#pragma unroll
    for (int off = 32; off > 0; off >>= 1) {
        s += __shfl_down(s, off, 64);
        q += __shfl_down(q, off, 64);
    }
    __shared__ float ss[4], qq[4];
    int wid = t >> 6, lane = t & 63;
    if (!lane) { ss[wid] = s; qq[wid] = q; }
    __syncthreads();
    s = ss[0] + ss[1] + ss[2] + ss[3];
    q = qq[0] + qq[1] + qq[2] + qq[3];
    float mu = s * (1.f / 768.f);
    float var = q * (1.f / 768.f) - mu * mu;
    float rs = rsqrtf(var + 1e-5f);
#pragma unroll
    for (int i = 0; i < 3; i++) {
        int c = t + i * 256;
        Y[(size_t)row * DIM_ + c] = (v[i] - mu) * rs * w[c] + bta[c];
    }
}

// ---------------- generic NT GEMM: C[M,Nc] = A[M,K] * W[Nc,K]^T (+bias)(+gelu|+res)
// All fp32. 128x128 tile, BK=16, 16x16 threads, 8x8 microtile.
// LDS is k-major so fragments read as float4 (ds_read_b128).
// Nc must be a multiple of 128 (768/2304/3072 all are); M edge handled by clamp+mask.
template <int ACT>  // 0 = none, 1 = exact erf-GELU
__launch_bounds__(256)
__global__ void gemm_nt(const float* __restrict__ A, const float* __restrict__ W,
                        const float* __restrict__ bias, const float* __restrict__ res,
                        float* __restrict__ C, int M, int Nc, int K) {
    __shared__ float As[16][128];
    __shared__ float Ws[16][128];
    const int tx = threadIdx.x, ty = threadIdx.y;
    const int tid = ty * 16 + tx;
    const int m0 = blockIdx.y * 128, n0 = blockIdx.x * 128;
    float acc[8][8] = {};
    for (int k0 = 0; k0 < K; k0 += 16) {
#pragma unroll
        for (int e = 0; e < 2; e++) {
            int L = tid + 256 * e;           // 0..511
            int row = L >> 2;                // 0..127
            int kq = (L & 3) * 4;            // 0,4,8,12
            int ar = m0 + row; ar = ar < M ? ar : M - 1;
            float4 av = *(const float4*)(A + (size_t)ar * K + k0 + kq);
            As[kq + 0][row] = av.x; As[kq + 1][row] = av.y;
            As[kq + 2][row] = av.z; As[kq + 3][row] = av.w;
            float4 wv = *(const float4*)(W + (size_t)(n0 + row) * K + k0 + kq);
            Ws[kq + 0][row] = wv.x; Ws[kq + 1][row] = wv.y;
            Ws[kq + 2][row] = wv.z; Ws[kq + 3][row] = wv.w;
        }
        __syncthreads();
#pragma unroll
        for (int kk = 0; kk < 16; kk++) {
            float4 a0 = *(const float4*)&As[kk][ty * 8];
            float4 a1 = *(const float4*)&As[kk][ty * 8 + 4];
            float4 b0 = *(const float4*)&Ws[kk][tx * 8];
            float4 b1 = *(const float4*)&Ws[kk][tx * 8 + 4];
            float a[8] = {a0.x, a0.y, a0.z, a0.w, a1.x, a1.y, a1.z, a1.w};
            float bb[8] = {b0.x, b0.y, b0.z, b0.w, b1.x, b1.y, b1.z, b1.w};
#pragma unroll
            for (int i = 0; i < 8; i++)
#pragma unroll
                for (int j = 0; j < 8; j++)
                    acc[i][j] += a[i] * bb[j];
        }
        __syncthreads();
    }
    // epilogue: bias -> (gelu) -> (+res) -> store, float4 stores (col always valid)
#pragma unroll
    for (int i = 0; i < 8; i++) {
        int row = m0 + ty * 8 + i;
        if (row >= M) continue;
        size_t base = (size_t)row * Nc + n0 + tx * 8;
#pragma unroll
        for (int jv = 0; jv < 2; jv++) {
            float tv[4];
#pragma unroll
            for (int c = 0; c < 4; c++) {
                int j = jv * 4 + c;
                float t = acc[i][j];
                if (bias) t += bias[n0 + tx * 8 + j];
                if (ACT == 1) t = 0.5f * t * (1.0f + erff(t * 0.70710678118654752f));
                tv[c] = t;
            }
            if (res) {
                float4 r = *(const float4*)(res + base + jv * 4);
                tv[0] += r.x; tv[1] += r.y; tv[2] += r.z; tv[3] += r.w;
            }
            float4 v4 = make_float4(tv[0], tv[1], tv[2], tv[3]);
            *(float4*)(C + base + jv * 4) = v4;
        }
    }
}

// ---------------- fused attention: scores + RPB + softmax + PV, one wave per q-row.
// qkv[M,2304] f32 (q|k|v per head, q unscaled: scale applied to scores).
// rpt: f32 [NRD,HEADS] for this layer. O: [M,768] f32 (o[b,n,h*64+d]).
__launch_bounds__(256)
__global__ void attn_k(const float* __restrict__ qkv, const float* __restrict__ rpt,
                       float* __restrict__ O) {
    int b = blockIdx.x / HEADS_, h = blockIdx.x % HEADS_;
    int w = threadIdx.x >> 6, lane = threadIdx.x & 63;
    int i = blockIdx.y * 4 + w;
    bool valid = i < N_;
    int ie = valid ? i : N_ - 1;  // all waves run full code so barriers stay uniform
    __shared__ float qs[4][64];
    __shared__ float sc[4][208];
    const float* qrow = qkv + (size_t)(b * N_ + ie) * QKV_ + h * HD_;
    qs[w][lane] = qrow[lane];
    __syncthreads();
    const float4* q4 = (const float4*)qs[w];
    // scores: lane handles keys j = lane, lane+64, ...
    for (int j = lane; j < N_; j += 64) {
        const float4* k4 = (const float4*)(qkv + (size_t)(b * N_ + j) * QKV_ + DIM_ + h * HD_);
        float dot = 0.f;
#pragma unroll
        for (int d = 0; d < 16; d++) {
            float4 kv = k4[d], qv = q4[d];
            dot += qv.x * kv.x + qv.y * kv.y + qv.z * kv.z + qv.w * kv.w;
        }
        // relative-position index (faithful port of the torch buffer construction)
        int idx;
        if (ie == 0)      idx = (j == 0) ? (NRD_ - 1) : (NRD_ - 3);
        else if (j == 0)  idx = NRD_ - 2;
        else {
            int pi = ie - 1, pj = j - 1;
            idx = ((pi / 14) - (pj / 14) + 13) * 27 + ((pi % 14) - (pj % 14) + 13);
        }
        sc[w][j] = dot * 0.125f + rpt[idx * HEADS_ + h];
    }
    // softmax over the lane-held entries (reads of own writes: no barrier needed)
    float mx = -3.0e38f;
    for (int j = lane; j < N_; j += 64) mx = fmaxf(mx, sc[w][j]);
#pragma unroll
    for (int off = 32; off > 0; off >>= 1) mx = fmaxf(mx, __shfl_xor(mx, off, 64));
    float sum = 0.f;
    for (int j = lane; j < N_; j += 64) {
        float e = __expf(sc[w][j] - mx);
        sc[w][j] = e;
        sum += e;
    }
#pragma unroll
    for (int off = 32; off > 0; off >>= 1) sum += __shfl_xor(sum, off, 64);
    float rinv = 1.f / sum;
    __syncthreads();
    // PV: lane = output dim d; V reads are 256B coalesced per j
    const float* vbase = qkv + (size_t)(b * N_) * QKV_ + 2 * DIM_ + h * HD_ + lane;
    float o = 0.f;
#pragma unroll 4
    for (int j = 0; j < N_; j++) o += sc[w][j] * vbase[(size_t)j * QKV_];
    o *= rinv;
    if (valid) O[(size_t)(b * N_ + i) * DIM_ + h * HD_ + lane] = o;
}

extern "C" void kernel_launch(void* const* d_in, const int* in_sizes, int n_in,
                              void* d_out, int out_size, void* d_ws, size_t ws_size,
                              hipStream_t stream) {
    (void)in_sizes; (void)n_in; (void)out_size; (void)ws_size;
    const float* x    = (const float*)d_in[0];
    const float* pew  = (const float*)d_in[1];   // patch_w [768,768]
    const float* peb  = (const float*)d_in[2];
    const float* cls  = (const float*)d_in[3];
    const float* n1w  = (const float*)d_in[4];
    const float* n1b  = (const float*)d_in[5];
    const float* qkvw = (const float*)d_in[6];   // [12,2304,768]
    const float* qb   = (const float*)d_in[7];
    const float* vb   = (const float*)d_in[8];
    const float* rpt  = (const float*)d_in[9];   // [12,732,12]
    const float* pw   = (const float*)d_in[10];  // [12,768,768]
    const float* pb   = (const float*)d_in[11];
    const float* n2w  = (const float*)d_in[12];
    const float* n2b  = (const float*)d_in[13];
    const float* f1w  = (const float*)d_in[14];  // [12,3072,768]
    const float* f1b  = (const float*)d_in[15];
    const float* f2w  = (const float*)d_in[16];  // [12,768,3072]
    const float* f2b_ = (const float*)d_in[17];
    const float* nfw  = (const float*)d_in[18];
    const float* nfb  = (const float*)d_in[19];

    // workspace layout (floats). total ~29.05M floats = 116.2 MB
    float* ws = (float*)d_ws;
    size_t off = 0;
    float* h  = ws;        off += (size_t)M_ * DIM_;   // persistent residual stream
    float* y  = ws + off;  off += (size_t)M_ * DIM_;   // LN out / attn out
    float* un = ws + off;  off += (size_t)M_ * FF_;    // union: qkv | mlp-hidden | patch bufs
    float* qbias = ws + off; off += QKV_;
    float* qkvb   = un;
    float* hidden = un;
    float* pmat   = un;
    float* pout   = un + (size_t)MP_ * DIM_;

    dim3 thr(16, 16);
    const int MT = (M_ + 127) / 128;  // 50 row tiles

    // patch embed
    patchify_k<<<(MP_ * DIM_ + 255) / 256, 256, 0, stream>>>(x, pmat);
    gemm_nt<0><<<dim3(DIM_ / 128, MP_ / 128), thr, 0, stream>>>(
        pmat, pew, peb, nullptr, pout, MP_, DIM_, DIM_);
    build_tokens_k<<<(M_ * DIM_ + 255) / 256, 256, 0, stream>>>(pout, cls, h);

    for (int l = 0; l < 12; l++) {
        layernorm_k<<<M_, 256, 0, stream>>>(h, n1w + l * DIM_, n1b + l * DIM_, y);
        qkvbias_k<<<9, 256, 0, stream>>>(qb + l * DIM_, vb + l * DIM_, qbias);
        gemm_nt<0><<<dim3(QKV_ / 128, MT), thr, 0, stream>>>(
            y, qkvw + (size_t)l * QKV_ * DIM_, qbias, nullptr, qkvb, M_, QKV_, DIM_);
        attn_k<<<dim3(B_ * HEADS_, (N_ + 3) / 4), 256, 0, stream>>>(
            qkvb, rpt + (size_t)l * NRD_ * HEADS_, y);
        gemm_nt<0><<<dim3(DIM_ / 128, MT), thr, 0, stream>>>(
            y, pw + (size_t)l * DIM_ * DIM_, pb + l * DIM_, h, h, M_, DIM_, DIM_);
        layernorm_k<<<M_, 256, 0, stream>>>(h, n2w + l * DIM_, n2b + l * DIM_, y);
        gemm_nt<1><<<dim3(FF_ / 128, MT), thr, 0, stream>>>(
            y, f1w + (size_t)l * FF_ * DIM_, f1b + l * FF_, nullptr, hidden, M_, FF_, DIM_);
        gemm_nt<0><<<dim3(DIM_ / 128, MT), thr, 0, stream>>>(
            hidden, f2w + (size_t)l * DIM_ * FF_, f2b_ + l * DIM_, h, h, M_, DIM_, FF_);
    }
    layernorm_k<<<M_, 256, 0, stream>>>(h, nfw, nfb, (float*)d_out);
}

// Round 3
// 6237.932 us; speedup vs baseline: 4.9560x; 4.9560x over previous
//
#include <hip/hip_runtime.h>
#include <hip/hip_bf16.h>

// ViT-B/16 forward, MI355X. Round 2: bf16 MFMA GEMMs (128x128 tile, BK=32,
// 16x16x32 mfma), LDS-staged fused attention. f32 residual stream, f32 I/O.
//
// B=32, IMG=224 -> 196 patches +cls = 197 tokens, DIM=768, HEADS=12, HD=64,
// FF=3072, DEPTH=12, NRD=732.

#define B_     32
#define DIM_   768
#define N_     197
#define M_     (B_*N_)      // 6304
#define NP_    196
#define MP_    (B_*NP_)     // 6272
#define HEADS_ 12
#define HD_    64
#define FF_    3072
#define NRD_   732
#define QKV_   2304

typedef unsigned short u16;
typedef unsigned int   u32;
typedef __attribute__((ext_vector_type(4))) float    f32x4;
typedef __attribute__((ext_vector_type(8))) u16      ushort8;
typedef __attribute__((ext_vector_type(8))) __bf16   bf16x8;

__device__ __forceinline__ float b2f(u16 u) {
    return __builtin_bit_cast(float, ((u32)u) << 16);
}
__device__ __forceinline__ u16 f2b(float f) {  // RNE f32->bf16
    u32 u = __builtin_bit_cast(u32, f);
    u32 r = u + 0x7fffu + ((u >> 16) & 1u);
    return (u16)(r >> 16);
}
__device__ __forceinline__ float lo16(u32 v) { return __builtin_bit_cast(float, v << 16); }
__device__ __forceinline__ float hi16(u32 v) { return __builtin_bit_cast(float, v & 0xffff0000u); }

__device__ __forceinline__ f32x4 mfma16(ushort8 a, ushort8 b, f32x4 c) {
    return __builtin_amdgcn_mfma_f32_16x16x32_bf16(
        __builtin_bit_cast(bf16x8, a), __builtin_bit_cast(bf16x8, b), c, 0, 0, 0);
}

// ---------------- f32 -> bf16 converters ----------------
__global__ void cvt_k(const float* __restrict__ src, u16* __restrict__ dst, int n8) {
    int g = blockIdx.x * 256 + threadIdx.x;
    if (g >= n8) return;
    size_t o = (size_t)g * 8;
    float4 f0 = *(const float4*)(src + o);
    float4 f1 = *(const float4*)(src + o + 4);
    ushort8 r;
    r[0]=f2b(f0.x); r[1]=f2b(f0.y); r[2]=f2b(f0.z); r[3]=f2b(f0.w);
    r[4]=f2b(f1.x); r[5]=f2b(f1.y); r[6]=f2b(f1.z); r[7]=f2b(f1.w);
    *(ushort8*)(dst + o) = r;
}

// one layer's 4 weight mats -> contiguous bf16 wbuf [qkv|proj|fc1|fc2]
#define SEG0 1769472   // 2304*768
#define SEG1 589824    // 768*768
#define SEG2 2359296   // 3072*768
#define SEG3 2359296   // 768*3072
__global__ void cvt4_k(const float* __restrict__ s0, const float* __restrict__ s1,
                       const float* __restrict__ s2, const float* __restrict__ s3,
                       u16* __restrict__ dst) {
    int g = blockIdx.x * 256 + threadIdx.x;
    if (g >= (SEG0+SEG1+SEG2+SEG3)/8) return;
    size_t o = (size_t)g * 8;
    const float* src; size_t lo_;
    if (o < SEG0)             { src = s0; lo_ = o; }
    else if (o < SEG0+SEG1)   { src = s1; lo_ = o - SEG0; }
    else if (o < (size_t)SEG0+SEG1+SEG2) { src = s2; lo_ = o - SEG0 - SEG1; }
    else                      { src = s3; lo_ = o - SEG0 - SEG1 - SEG2; }
    float4 f0 = *(const float4*)(src + lo_);
    float4 f1 = *(const float4*)(src + lo_ + 4);
    ushort8 r;
    r[0]=f2b(f0.x); r[1]=f2b(f0.y); r[2]=f2b(f0.z); r[3]=f2b(f0.w);
    r[4]=f2b(f1.x); r[5]=f2b(f1.y); r[6]=f2b(f1.z); r[7]=f2b(f1.w);
    *(ushort8*)(dst + o) = r;
}

// ---------------- patchify: x[B,3,224,224] -> P bf16 [6272,768]
__global__ void patchify_k(const float* __restrict__ X, u16* __restrict__ P) {
    int idx = blockIdx.x * 256 + threadIdx.x;
    if (idx >= MP_ * DIM_) return;
    int row = idx / DIM_, k = idx - row * DIM_;
    int b = row / NP_, p = row - b * NP_;
    int gy = p / 14, gx = p - gy * 14;
    int c = k >> 8, r = k & 255;
    int py = r >> 4, px = r & 15;
    P[idx] = f2b(X[((b * 3 + c) * 224 + gy * 16 + py) * 224 + gx * 16 + px]);
}

// ---------------- tokens: f32 patch-GEMM out + cls -> h f32
__global__ void build_tokens_k(const float* __restrict__ P, const float* __restrict__ cls,
                               float* __restrict__ T) {
    int idx = blockIdx.x * 256 + threadIdx.x;
    if (idx >= M_ * DIM_) return;
    int row = idx / DIM_, c = idx - row * DIM_;
    int b = row / N_, t = row - b * N_;
    T[idx] = (t == 0) ? cls[c] : P[(size_t)(b * NP_ + t - 1) * DIM_ + c];
}

// ---------------- qkv bias = concat(q_bias, 0, v_bias)  (f32)
__global__ void qkvbias_k(const float* __restrict__ qb, const float* __restrict__ vb,
                          float* __restrict__ out) {
    int n = blockIdx.x * 256 + threadIdx.x;
    if (n >= QKV_) return;
    out[n] = (n < DIM_) ? qb[n] : (n < 2 * DIM_ ? 0.f : vb[n - 2 * DIM_]);
}

// ---------------- LayerNorm (biased var, eps=1e-5). One block(256) per row.
template <int OUTBF>
__global__ void layernorm_k(const float* __restrict__ X, const float* __restrict__ w,
                            const float* __restrict__ bta, void* __restrict__ Yv) {
    int row = blockIdx.x;
    const float* x = X + (size_t)row * DIM_;
    int t = threadIdx.x;
    float v[3]; float s = 0.f, q = 0.f;
#pragma unroll
    for (int i = 0; i < 3; i++) { float u = x[t + i * 256]; v[i] = u; s += u; q += u * u; }
#pragma unroll
    for (int off = 32; off > 0; off >>= 1) {
        s += __shfl_down(s, off, 64);
        q += __shfl_down(q, off, 64);
    }
    __shared__ float ss[4], qq[4];
    int wid = t >> 6, lane = t & 63;
    if (!lane) { ss[wid] = s; qq[wid] = q; }
    __syncthreads();
    s = ss[0] + ss[1] + ss[2] + ss[3];
    q = qq[0] + qq[1] + qq[2] + qq[3];
    float mu = s * (1.f / 768.f);
    float var = q * (1.f / 768.f) - mu * mu;
    float rs = rsqrtf(var + 1e-5f);
#pragma unroll
    for (int i = 0; i < 3; i++) {
        int c = t + i * 256;
        float o = (v[i] - mu) * rs * w[c] + bta[c];
        if (OUTBF) ((u16*)Yv)[(size_t)row * DIM_ + c] = f2b(o);
        else       ((float*)Yv)[(size_t)row * DIM_ + c] = o;
    }
}

// ---------------- MFMA NT GEMM: C[M,Nc] = A[M,K](bf16) * W[Nc,K]^T(bf16)
// 128x128 tile, BK=32, 4 waves each 64x64 (4x4 of 16x16x32 mfma).
// Nc % 128 == 0; M edge clamped on load, masked on store.
template <int ACT, int OUTBF>   // ACT: erf-GELU; OUTBF: store bf16 else f32
__launch_bounds__(256)
__global__ void gemm_bt(const u16* __restrict__ A, const u16* __restrict__ W,
                        const float* __restrict__ bias, const float* res,
                        void* Cv, int M, int Nc, int K) {
    __shared__ u16 As[128 * 32];
    __shared__ u16 Ws[128 * 32];
    const int tid = threadIdx.x;
    const int lane = tid & 63, w = tid >> 6;
    const int wm = w & 1, wn = w >> 1;
    const int m0 = blockIdx.y * 128, n0 = blockIdx.x * 128;
    const int r0 = tid >> 2, sg = (tid & 3) * 8;  // staging: 16B per thread, 2 passes
    f32x4 acc[4][4] = {};
    for (int k0 = 0; k0 < K; k0 += 32) {
        int ar0 = m0 + r0;      if (ar0 >= M) ar0 = M - 1;
        int ar1 = m0 + r0 + 64; if (ar1 >= M) ar1 = M - 1;
        ushort8 a0 = *(const ushort8*)(A + (size_t)ar0 * K + k0 + sg);
        ushort8 a1 = *(const ushort8*)(A + (size_t)ar1 * K + k0 + sg);
        ushort8 w0 = *(const ushort8*)(W + (size_t)(n0 + r0) * K + k0 + sg);
        ushort8 w1 = *(const ushort8*)(W + (size_t)(n0 + r0 + 64) * K + k0 + sg);
        __syncthreads();   // previous iteration's fragment reads done
        *(ushort8*)(As + r0 * 32 + sg) = a0;
        *(ushort8*)(As + (r0 + 64) * 32 + sg) = a1;
        *(ushort8*)(Ws + r0 * 32 + sg) = w0;
        *(ushort8*)(Ws + (r0 + 64) * 32 + sg) = w1;
        __syncthreads();
        ushort8 af[4], bfr[4];
#pragma unroll
        for (int mi = 0; mi < 4; mi++)
            af[mi] = *(const ushort8*)(As + (wm * 64 + mi * 16 + (lane & 15)) * 32 + (lane >> 4) * 8);
#pragma unroll
        for (int ni = 0; ni < 4; ni++)
            bfr[ni] = *(const ushort8*)(Ws + (wn * 64 + ni * 16 + (lane & 15)) * 32 + (lane >> 4) * 8);
#pragma unroll
        for (int mi = 0; mi < 4; mi++)
#pragma unroll
            for (int ni = 0; ni < 4; ni++)
                acc[mi][ni] = mfma16(af[mi], bfr[ni], acc[mi][ni]);
    }
    // epilogue: D(row,col): row = quad*4+reg, col = lane&15 (m89-verified layout)
    const int cb = n0 + wn * 64 + (lane & 15);
    const int rb = m0 + wm * 64 + ((lane >> 4) * 4);
#pragma unroll
    for (int ni = 0; ni < 4; ni++) {
        int col = cb + ni * 16;
        float bv = bias ? bias[col] : 0.f;
#pragma unroll
        for (int mi = 0; mi < 4; mi++) {
#pragma unroll
            for (int rg = 0; rg < 4; rg++) {
                int row = rb + mi * 16 + rg;
                if (row >= M) continue;
                float t = acc[mi][ni][rg] + bv;
                if (ACT) t = 0.5f * t * (1.f + erff(t * 0.70710678118654752f));
                if (res) t += res[(size_t)row * Nc + col];
                if (OUTBF) ((u16*)Cv)[(size_t)row * Nc + col] = f2b(t);
                else       ((float*)Cv)[(size_t)row * Nc + col] = t;
            }
        }
    }
}

// ---------------- fused attention, LDS-staged.
// qkv bf16 [M,2304] (q|k|v); rpt f32 [NRD,12] for this layer; O bf16 [M,768].
// grid (384, 4): block = (b,h), 52 q-rows; 4 waves x 13 rows.
__launch_bounds__(256)
__global__ void attn2_k(const u16* __restrict__ qkv, const float* __restrict__ rpt,
                        u16* __restrict__ O) {
    __shared__ u16 Ks[197 * 66];   // K[j][d], stride 66 (conflict-free b32)
    __shared__ u16 Vt[64 * 200];   // V^T[d][j], stride 200 (b128 rows)
    __shared__ u16 Qs[52 * 66];
    __shared__ u16 Ps[52 * 200];   // softmaxed P, bf16
    const int b = blockIdx.x / HEADS_, hh = blockIdx.x % HEADS_;
    const int i0 = blockIdx.y * 52;
    const int t = threadIdx.x;
    const int w = t >> 6, lane = t & 63;
    const size_t base = (size_t)b * N_ * QKV_ + hh * HD_;
    // ---- stage K rows + V transposed (197*64 each)
    for (int g = t; g < 1576; g += 256) {
        int j = g >> 3, d = (g & 7) * 8;
        ushort8 kv = *(const ushort8*)(qkv + base + (size_t)j * QKV_ + 768 + d);
        uint4 ku = __builtin_bit_cast(uint4, kv);
        u32* kd = (u32*)Ks + j * 33 + (d >> 1);
        kd[0] = ku.x; kd[1] = ku.y; kd[2] = ku.z; kd[3] = ku.w;
        ushort8 vv = *(const ushort8*)(qkv + base + (size_t)j * QKV_ + 1536 + d);
#pragma unroll
        for (int e = 0; e < 8; e++) Vt[(d + e) * 200 + j] = ((const u16*)&vv)[e];
    }
    if (t < 64) { Vt[t * 200 + 197] = 0; Vt[t * 200 + 198] = 0; Vt[t * 200 + 199] = 0; }
    // ---- stage Q (row-clamped)
    for (int g = t; g < 416; g += 256) {
        int r = g >> 3, d = (g & 7) * 8;
        int i = i0 + r; if (i > 196) i = 196;
        ushort8 qv = *(const ushort8*)(qkv + base + (size_t)i * QKV_ + d);
        uint4 qu = __builtin_bit_cast(uint4, qv);
        u32* qd = (u32*)Qs + r * 33 + (d >> 1);
        qd[0] = qu.x; qd[1] = qu.y; qd[2] = qu.z; qd[3] = qu.w;
    }
    __syncthreads();

    for (int rr = 0; rr < 13; rr++) {
        const int r = w * 13 + rr;
        const int i = i0 + r;
        if (i > 196) continue;               // wave-uniform
        float qf[64];
        const u32* qd = (const u32*)Qs + r * 33;
#pragma unroll
        for (int dq = 0; dq < 32; dq++) { u32 v = qd[dq]; qf[2*dq] = lo16(v); qf[2*dq+1] = hi16(v); }
        float s[4];
#pragma unroll
        for (int ssl = 0; ssl < 4; ssl++) {
            int j = lane + 64 * ssl;
            if (j < 197) {
                const u32* kd = (const u32*)Ks + j * 33;
                float dot = 0.f;
#pragma unroll
                for (int dq = 0; dq < 32; dq++) {
                    u32 v = kd[dq];
                    dot = fmaf(lo16(v), qf[2*dq], dot);
                    dot = fmaf(hi16(v), qf[2*dq+1], dot);
                }
                int idx;
                if (i == 0)      idx = (j == 0) ? (NRD_-1) : (NRD_-3);
                else if (j == 0) idx = NRD_-2;
                else {
                    int pi = i - 1, pj = j - 1;
                    idx = ((pi/14) - (pj/14) + 13) * 27 + ((pi%14) - (pj%14) + 13);
                }
                s[ssl] = dot * 0.125f + rpt[idx * HEADS_ + hh];
            } else s[ssl] = -INFINITY;
        }
        float mx = fmaxf(fmaxf(s[0], s[1]), fmaxf(s[2], s[3]));
#pragma unroll
        for (int o = 32; o > 0; o >>= 1) mx = fmaxf(mx, __shfl_xor(mx, o, 64));
        float e[4], sum = 0.f;
#pragma unroll
        for (int ssl = 0; ssl < 4; ssl++) {
            e[ssl] = (s[ssl] > -1e37f) ? __expf(s[ssl] - mx) : 0.f;
            sum += e[ssl];
        }
#pragma unroll
        for (int o = 32; o > 0; o >>= 1) sum += __shfl_xor(sum, o, 64);
        float rinv = 1.f / sum;
#pragma unroll
        for (int ssl = 0; ssl < 4; ssl++) {
            int j = lane + 64 * ssl;
            if (j < 197)      Ps[r * 200 + j] = f2b(e[ssl] * rinv);
            else if (j < 200) Ps[r * 200 + j] = 0;
        }
        // PV: lane = output dim d
        float o = 0.f;
#pragma unroll
        for (int jb = 0; jb < 200; jb += 8) {
            ushort8 p8 = *(const ushort8*)(Ps + r * 200 + jb);
            ushort8 v8 = *(const ushort8*)(Vt + lane * 200 + jb);
            uint4 pu = __builtin_bit_cast(uint4, p8);
            uint4 vu = __builtin_bit_cast(uint4, v8);
            u32 pa[4] = {pu.x, pu.y, pu.z, pu.w};
            u32 va[4] = {vu.x, vu.y, vu.z, vu.w};
#pragma unroll
            for (int q2 = 0; q2 < 4; q2++) {
                o = fmaf(lo16(pa[q2]), lo16(va[q2]), o);
                o = fmaf(hi16(pa[q2]), hi16(va[q2]), o);
            }
        }
        O[(size_t)(b * N_ + i) * DIM_ + hh * HD_ + lane] = f2b(o);
    }
}

extern "C" void kernel_launch(void* const* d_in, const int* in_sizes, int n_in,
                              void* d_out, int out_size, void* d_ws, size_t ws_size,
                              hipStream_t stream) {
    (void)in_sizes; (void)n_in; (void)out_size; (void)ws_size;
    const float* x    = (const float*)d_in[0];
    const float* pew  = (const float*)d_in[1];
    const float* peb  = (const float*)d_in[2];
    const float* cls  = (const float*)d_in[3];
    const float* n1w  = (const float*)d_in[4];
    const float* n1b  = (const float*)d_in[5];
    const float* qkvw = (const float*)d_in[6];
    const float* qb   = (const float*)d_in[7];
    const float* vb   = (const float*)d_in[8];
    const float* rpt  = (const float*)d_in[9];
    const float* pw   = (const float*)d_in[10];
    const float* pb   = (const float*)d_in[11];
    const float* n2w  = (const float*)d_in[12];
    const float* n2b  = (const float*)d_in[13];
    const float* f1w  = (const float*)d_in[14];
    const float* f1b  = (const float*)d_in[15];
    const float* f2w  = (const float*)d_in[16];
    const float* f2b_ = (const float*)d_in[17];
    const float* nfw  = (const float*)d_in[18];
    const float* nfb  = (const float*)d_in[19];

    // workspace (floats): h | y(bf16) | un | wbuf(bf16) | qbias  ~= 82 MB
    float* ws = (float*)d_ws;
    float* h     = ws;                                   // 4,841,472 f32
    u16*   y     = (u16*)(ws + 4841472);                 // bf16 [M,768]
    float* un    = ws + 4841472 + 2420736;               // 9,682,944 f32 union
    u16*   wbuf  = (u16*)(un + 9682944);                 // 7,077,888 bf16
    float* qbias = (float*)(wbuf + 7077888);             // 2304 f32
    u16*   qkvb   = (u16*)un;                            // bf16 [M,2304]
    u16*   hidden = (u16*)un;                            // bf16 [M,3072]
    u16*   pmat   = (u16*)un;                            // bf16 [6272,768]
    float* pout   = un + 4816896;                        // f32  [6272,768]

    const int MT = (M_ + 127) / 128;  // 50

    // patch embed
    cvt_k<<<288, 256, 0, stream>>>(pew, wbuf, SEG1 / 8);
    patchify_k<<<(MP_ * DIM_ + 255) / 256, 256, 0, stream>>>(x, pmat);
    gemm_bt<0, 0><<<dim3(6, 49), 256, 0, stream>>>(pmat, wbuf, peb, nullptr, pout,
                                                   MP_, DIM_, DIM_);
    build_tokens_k<<<(M_ * DIM_ + 255) / 256, 256, 0, stream>>>(pout, cls, h);

    for (int l = 0; l < 12; l++) {
        layernorm_k<1><<<M_, 256, 0, stream>>>(h, n1w + l * DIM_, n1b + l * DIM_, y);
        cvt4_k<<<3456, 256, 0, stream>>>(qkvw + (size_t)l * SEG0, pw + (size_t)l * SEG1,
                                         f1w + (size_t)l * SEG2, f2w + (size_t)l * SEG3, wbuf);
        qkvbias_k<<<9, 256, 0, stream>>>(qb + l * DIM_, vb + l * DIM_, qbias);
        gemm_bt<0, 1><<<dim3(18, MT), 256, 0, stream>>>(y, wbuf, qbias, nullptr, qkvb,
                                                        M_, QKV_, DIM_);
        attn2_k<<<dim3(384, 4), 256, 0, stream>>>(qkvb, rpt + (size_t)l * NRD_ * HEADS_, y);
        gemm_bt<0, 0><<<dim3(6, MT), 256, 0, stream>>>(y, wbuf + SEG0, pb + l * DIM_, h, h,
                                                       M_, DIM_, DIM_);
        layernorm_k<1><<<M_, 256, 0, stream>>>(h, n2w + l * DIM_, n2b + l * DIM_, y);
        gemm_bt<1, 1><<<dim3(24, MT), 256, 0, stream>>>(y, wbuf + SEG0 + SEG1, f1b + l * FF_,
                                                        nullptr, hidden, M_, FF_, DIM_);
        gemm_bt<0, 0><<<dim3(6, MT), 256, 0, stream>>>(hidden, wbuf + SEG0 + SEG1 + SEG2,
                                                       f2b_ + l * DIM_, h, h, M_, DIM_, FF_);
    }
    layernorm_k<0><<<M_, 256, 0, stream>>>(h, nfw, nfb, d_out);
}